// Round 4
// baseline (278.394 us; speedup 1.0000x reference)
//
#include <hip/hip_runtime.h>
#include <math.h>

#define BATCH 4
#define SEQ   4096
#define EMB   1024
#define HD    128
#define MROWS (BATCH*SEQ)
#define SCALE 0.08838834764831844f   // 1/sqrt(128)
#define NJOBS 204                    // split-KV jobs per batch (BQ=64, chunk=12 kv-tiles)
#define MAXC  6

typedef __attribute__((ext_vector_type(8))) short bf16x8;   // MFMA A/B frag (4 VGPR)
typedef __attribute__((ext_vector_type(4))) short short4v;  // 8B LDS store
typedef __attribute__((ext_vector_type(4))) float f32x4;    // MFMA C/D frag
typedef __attribute__((ext_vector_type(4))) int   i32x4;    // 16B copy

static __device__ __forceinline__ unsigned short f2bf(float f) {
    unsigned int u = __float_as_uint(f);
    u += 0x7fff + ((u >> 16) & 1);       // RNE
    return (unsigned short)(u >> 16);
}
static __device__ __forceinline__ unsigned int f2bf2(float lo, float hi) {
    return (unsigned int)f2bf(lo) | ((unsigned int)f2bf(hi) << 16);
}
static __device__ __forceinline__ float bf2f(unsigned short s) {
    return __uint_as_float((unsigned int)s << 16);
}

// ---------------- W transpose + bf16 (+ fold q-scale) ----------------
__global__ __launch_bounds__(128) void wtrans_kernel(
    const float* __restrict__ Wq, const float* __restrict__ Wk,
    const float* __restrict__ Wv, unsigned short* __restrict__ Wt)
{
    const int w  = blockIdx.y;
    const float* W = (w == 0) ? Wq : (w == 1) ? Wk : Wv;
    const float sc = (w == 0) ? SCALE : 1.0f;
    unsigned short* dst = Wt + (size_t)w * 131072;
    const int n  = threadIdx.x;
    const int k0 = blockIdx.x * 64;
    for (int jc = 0; jc < 8; ++jc) {
        float v[8];
#pragma unroll
        for (int je = 0; je < 8; ++je)
            v[je] = W[(size_t)(k0 + jc * 8 + je) * HD + n] * sc;
        i32x4 p;
        p[0] = f2bf2(v[0], v[1]); p[1] = f2bf2(v[2], v[3]);
        p[2] = f2bf2(v[4], v[5]); p[3] = f2bf2(v[6], v[7]);
        *(i32x4*)&dst[(size_t)n * 1024 + k0 + jc * 8] = p;
    }
}

// ---------------- QKV projection: MFMA, W-frags direct from global ----------------
// grid (3, 256): x = which W, y = 64-row tile. 256 thr = 4 waves (2x2 of 32x64).
// x tile double-buffered in LDS (1 barrier/iter); B operand read straight from Wt (L2-hot).
__global__ __launch_bounds__(256) void qkv_kernel(
    const float* __restrict__ x, const unsigned short* __restrict__ Wt,
    unsigned short* __restrict__ qb, unsigned short* __restrict__ kb,
    unsigned short* __restrict__ vtb)
{
    __shared__ __align__(16) unsigned short As[2][64 * 72];   // 2 x 9216 B

    const int w   = blockIdx.x;
    const int m0  = blockIdx.y * 64;
    const unsigned short* Wm = Wt + (size_t)w * 131072;
    const int t    = threadIdx.x;
    const int lane = t & 63, wv = t >> 6;
    const int quad = lane >> 4, l16 = lane & 15;
    const int mhalf = wv >> 1, nhalf = wv & 1;

    f32x4 acc[2][4];
#pragma unroll
    for (int i = 0; i < 2; ++i)
#pragma unroll
        for (int j = 0; j < 4; ++j) acc[i][j] = (f32x4){0.f, 0.f, 0.f, 0.f};

    // x prefetch: thread -> row t>>2, 16 consecutive floats at col (t&3)*16
    const int xrow = t >> 2, xcol = (t & 3) * 16;
    float4 xp[4];
#pragma unroll
    for (int i = 0; i < 4; ++i)
        xp[i] = *(const float4*)&x[(size_t)(m0 + xrow) * EMB + 0 + xcol + i * 4];

    for (int kt = 0; kt < EMB; kt += 64) {
        unsigned short* ab = As[(kt >> 6) & 1];
        // write prefetched x (converted) into current buffer
        i32x4 p0, p1;
        p0[0] = f2bf2(xp[0].x, xp[0].y); p0[1] = f2bf2(xp[0].z, xp[0].w);
        p0[2] = f2bf2(xp[1].x, xp[1].y); p0[3] = f2bf2(xp[1].z, xp[1].w);
        p1[0] = f2bf2(xp[2].x, xp[2].y); p1[1] = f2bf2(xp[2].z, xp[2].w);
        p1[2] = f2bf2(xp[3].x, xp[3].y); p1[3] = f2bf2(xp[3].z, xp[3].w);
        *(i32x4*)&ab[xrow * 72 + xcol]     = p0;
        *(i32x4*)&ab[xrow * 72 + xcol + 8] = p1;
        if (kt + 64 < EMB) {
#pragma unroll
            for (int i = 0; i < 4; ++i)
                xp[i] = *(const float4*)&x[(size_t)(m0 + xrow) * EMB + kt + 64 + xcol + i * 4];
        }
        __syncthreads();
#pragma unroll
        for (int ks = 0; ks < 2; ++ks) {
            bf16x8 aA[2], aB[4];
#pragma unroll
            for (int mt = 0; mt < 2; ++mt)
                aA[mt] = *(const bf16x8*)&ab[(mhalf * 32 + mt * 16 + l16) * 72 + ks * 32 + quad * 8];
#pragma unroll
            for (int nt = 0; nt < 4; ++nt)
                aB[nt] = *(const bf16x8*)&Wm[(size_t)(nhalf * 64 + nt * 16 + l16) * 1024 +
                                             kt + ks * 32 + quad * 8];
#pragma unroll
            for (int mt = 0; mt < 2; ++mt)
#pragma unroll
                for (int nt = 0; nt < 4; ++nt)
                    acc[mt][nt] = __builtin_amdgcn_mfma_f32_16x16x32_bf16(
                        aA[mt], aB[nt], acc[mt][nt], 0, 0, 0);
        }
        __syncthreads();   // protect buffer reuse (written again at kt+128)
    }

    // epilogue: C -> LDS (layout per output), then coalesced copy out
    unsigned short* Cs = &As[0][0];
    if (w < 2) {
        // natural [s][h], pad 136
#pragma unroll
        for (int mt = 0; mt < 2; ++mt)
#pragma unroll
            for (int nt = 0; nt < 4; ++nt)
#pragma unroll
                for (int rr = 0; rr < 4; ++rr)
                    Cs[(mhalf * 32 + mt * 16 + quad * 4 + rr) * 136 +
                       nhalf * 64 + nt * 16 + l16] = f2bf(acc[mt][nt][rr]);
        __syncthreads();
        unsigned short* dst = ((w == 0) ? qb : kb) + (size_t)m0 * HD;
#pragma unroll
        for (int i = 0; i < 4; ++i) {
            int g = i * 256 + t;
            int row = g >> 4, seg = g & 15;
            *(i32x4*)&dst[(size_t)row * 128 + seg * 8] = *(const i32x4*)&Cs[row * 136 + seg * 8];
        }
    } else {
        // transposed [h][s], pad 72
#pragma unroll
        for (int mt = 0; mt < 2; ++mt)
#pragma unroll
            for (int nt = 0; nt < 4; ++nt) {
                short4v p;
                p[0] = (short)f2bf(acc[mt][nt][0]); p[1] = (short)f2bf(acc[mt][nt][1]);
                p[2] = (short)f2bf(acc[mt][nt][2]); p[3] = (short)f2bf(acc[mt][nt][3]);
                *(short4v*)&Cs[(nhalf * 64 + nt * 16 + l16) * 72 +
                               mhalf * 32 + mt * 16 + quad * 4] = p;
            }
        __syncthreads();
        const int b = m0 >> 12, s0 = m0 & 4095;
#pragma unroll
        for (int i = 0; i < 4; ++i) {
            int g = i * 256 + t;
            int h = g >> 3, seg = g & 7;
            *(i32x4*)&vtb[(size_t)b * (HD * SEQ) + (size_t)h * SEQ + s0 + seg * 8] =
                *(const i32x4*)&Cs[h * 72 + seg * 8];
        }
    }
}

// ---------------- Flash attention: split-KV, BQ=64, direct-global K frags ----------------
// Job = (b, qi 64-row tile, chunk c of 12 kv-tiles). grid (204, 4), 256 thr = 4 waves.
// K fragments: b128 straight from global (L2-hot). V: reg-prefetch -> double-buffered LDS.
// One __syncthreads per kv-tile.
#define PADV 72
#define PADP 72

__global__ __launch_bounds__(256, 3) void flash_kernel(
    const unsigned short* __restrict__ qb, const unsigned short* __restrict__ kb,
    const unsigned short* __restrict__ vtb, unsigned short* __restrict__ Opart,
    float* __restrict__ mbuf, float* __restrict__ lbuf)
{
    __shared__ __align__(16) unsigned short Vt[2][128 * PADV];   // 36.9 KB
    __shared__ __align__(16) unsigned short Pt[64 * PADP];       //  9.2 KB

    const int t    = threadIdx.x;
    const int lane = t & 63, w = t >> 6;
    const int quad = lane >> 4, l16 = lane & 15;
    const int b    = blockIdx.y;

    // decode job j -> (qi, c): group g = qi/12 has chunk-count g+1
    const int j = blockIdx.x;
    int g = 0, s = 0;
#pragma unroll
    for (int gg = 0; gg < 5; ++gg)
        if (j >= s + 12 * (g + 1)) { s += 12 * (g + 1); ++g; }
    const int idx = j - s;
    const int qi  = 12 * g + idx / (g + 1);
    const int c   = idx % (g + 1);

    const int qrow = qi * 64 + w * 16 + l16;
    const int jbeg = c * 12;
    const int jend = min(jbeg + 12, qi + 1);

    bf16x8 qf[4];
    {
        const unsigned short* qp = qb + ((size_t)b * SEQ + qrow) * HD;
#pragma unroll
        for (int ks = 0; ks < 4; ++ks)
            qf[ks] = *(const bf16x8*)&qp[ks * 32 + quad * 8];
    }

    f32x4 O[8];
#pragma unroll
    for (int i = 0; i < 8; ++i) O[i] = (f32x4){0.f, 0.f, 0.f, 0.f};
    float m_run = -1e30f, l_run = 0.f;

    const unsigned short* kbb  = kb  + (size_t)b * SEQ * HD;
    const unsigned short* vtbb = vtb + (size_t)b * HD * SEQ;
    const int vh = t >> 3, vs8 = t & 7;   // V prefetch mapping: 2 rows/thread-group

    // prologue prefetch
    bf16x8 kf[16];
#pragma unroll
    for (int mt = 0; mt < 4; ++mt)
#pragma unroll
        for (int ks = 0; ks < 4; ++ks)
            kf[mt * 4 + ks] = *(const bf16x8*)&kbb[((size_t)jbeg * 64 + mt * 16 + l16) * HD +
                                                   ks * 32 + quad * 8];
    i32x4 vpref[4];
#pragma unroll
    for (int i = 0; i < 4; ++i) {
        int gg = i * 256 + t;
        vpref[i] = *(const i32x4*)&vtbb[(size_t)(gg >> 3) * SEQ + jbeg * 64 + (gg & 7) * 8];
    }

    for (int j0 = jbeg; j0 < jend; ++j0) {
        unsigned short* vb = Vt[j0 & 1];
        // write prefetched V into current buffer (safe: last readers separated by prev barrier)
#pragma unroll
        for (int i = 0; i < 4; ++i) {
            int gg = i * 256 + t;
            *(i32x4*)&vb[(gg >> 3) * PADV + (gg & 7) * 8] = vpref[i];
        }
        if (j0 + 1 < jend) {
#pragma unroll
            for (int i = 0; i < 4; ++i) {
                int gg = i * 256 + t;
                vpref[i] = *(const i32x4*)&vtbb[(size_t)(gg >> 3) * SEQ + (j0 + 1) * 64 + (gg & 7) * 8];
            }
        }
        __syncthreads();

        // ---- S^T = K . Q^T  (K frags already in regs) ----
        f32x4 st[4];
#pragma unroll
        for (int mt = 0; mt < 4; ++mt) {
            f32x4 a = (f32x4){0.f, 0.f, 0.f, 0.f};
#pragma unroll
            for (int ks = 0; ks < 4; ++ks)
                a = __builtin_amdgcn_mfma_f32_16x16x32_bf16(kf[mt * 4 + ks], qf[ks], a, 0, 0, 0);
            st[mt] = a;
        }
        // prefetch K frags for next tile (overwrites after consumption)
        if (j0 + 1 < jend) {
#pragma unroll
            for (int mt = 0; mt < 4; ++mt)
#pragma unroll
                for (int ks = 0; ks < 4; ++ks)
                    kf[mt * 4 + ks] = *(const bf16x8*)&kbb[((size_t)(j0 + 1) * 64 + mt * 16 + l16) * HD +
                                                           ks * 32 + quad * 8];
        }

        // ---- causal mask (skip when tile fully valid for this wave) ----
        if (j0 * 64 + 63 > qi * 64 + w * 16) {
#pragma unroll
            for (int mt = 0; mt < 4; ++mt)
#pragma unroll
                for (int rr = 0; rr < 4; ++rr) {
                    int kv = j0 * 64 + mt * 16 + quad * 4 + rr;
                    if (kv > qrow) st[mt][rr] = -1e30f;
                }
        }

        // ---- online softmax (lane owns one q-row) ----
        float mx = -1e30f;
#pragma unroll
        for (int mt = 0; mt < 4; ++mt)
#pragma unroll
            for (int rr = 0; rr < 4; ++rr) mx = fmaxf(mx, st[mt][rr]);
        mx = fmaxf(mx, __shfl_xor(mx, 16));
        mx = fmaxf(mx, __shfl_xor(mx, 32));
        const float m_new = fmaxf(m_run, mx);
        const float alpha = __expf(m_run - m_new);
        float psum = 0.f;
#pragma unroll
        for (int mt = 0; mt < 4; ++mt)
#pragma unroll
            for (int rr = 0; rr < 4; ++rr) {
                float p = __expf(st[mt][rr] - m_new);
                st[mt][rr] = p;
                psum += p;
            }
        psum += __shfl_xor(psum, 16);
        psum += __shfl_xor(psum, 32);
        m_run = m_new;
        l_run = l_run * alpha + psum;

        // ---- P^T -> LDS (wave-private rows, no barrier needed) ----
#pragma unroll
        for (int mt = 0; mt < 4; ++mt) {
            short4v p;
            p[0] = (short)f2bf(st[mt][0]); p[1] = (short)f2bf(st[mt][1]);
            p[2] = (short)f2bf(st[mt][2]); p[3] = (short)f2bf(st[mt][3]);
            *(short4v*)&Pt[(w * 16 + l16) * PADP + mt * 16 + quad * 4] = p;
        }

#pragma unroll
        for (int i = 0; i < 8; ++i) {
            O[i][0] *= alpha; O[i][1] *= alpha; O[i][2] *= alpha; O[i][3] *= alpha;
        }

        // ---- O^T += V^T . P^T ----
        bf16x8 pf0 = *(const bf16x8*)&Pt[(w * 16 + l16) * PADP + quad * 8];
        bf16x8 pf1 = *(const bf16x8*)&Pt[(w * 16 + l16) * PADP + 32 + quad * 8];
#pragma unroll
        for (int mt = 0; mt < 8; ++mt) {
            bf16x8 vf0 = *(const bf16x8*)&vb[(mt * 16 + l16) * PADV + quad * 8];
            bf16x8 vf1 = *(const bf16x8*)&vb[(mt * 16 + l16) * PADV + 32 + quad * 8];
            O[mt] = __builtin_amdgcn_mfma_f32_16x16x32_bf16(vf0, pf0, O[mt], 0, 0, 0);
            O[mt] = __builtin_amdgcn_mfma_f32_16x16x32_bf16(vf1, pf1, O[mt], 0, 0, 0);
        }
    }

    // ---- partial epilogue: unnormalized O (bf16) + m,l ----
    const int r = w * 16 + l16;
    const size_t jobbase = (size_t)b * NJOBS + j;
    unsigned short* po = Opart + jobbase * (64 * 128) + (size_t)r * 128;
#pragma unroll
    for (int mt = 0; mt < 8; ++mt) {
        short4v p;
        p[0] = (short)f2bf(O[mt][0]); p[1] = (short)f2bf(O[mt][1]);
        p[2] = (short)f2bf(O[mt][2]); p[3] = (short)f2bf(O[mt][3]);
        *(short4v*)&po[mt * 16 + quad * 4] = p;
    }
    if (quad == 0) {
        mbuf[jobbase * 64 + r] = m_run;
        lbuf[jobbase * 64 + r] = l_run;
    }
}

// ---------------- Combine partials ----------------
// grid (64, 4), 256 thr: thread -> q-row t>>2, 32 head cols at (t&3)*32.
__global__ __launch_bounds__(256) void combine_kernel(
    const unsigned short* __restrict__ Opart, const float* __restrict__ mbuf,
    const float* __restrict__ lbuf, float* __restrict__ out)
{
    const int qi = blockIdx.x, b = blockIdx.y;
    const int g  = qi / 12;
    const int nc = g + 1;
    const int j0 = 6 * g * (g + 1) + (qi - 12 * g) * (g + 1);   // first job id for this q-tile
    const int t = threadIdx.x;
    const int row = t >> 2, cg = (t & 3) * 32;

    float mv[MAXC], lv[MAXC];
    float M = -1e30f;
    for (int c2 = 0; c2 < nc; ++c2) {
        const size_t jb = (size_t)b * NJOBS + j0 + c2;
        mv[c2] = mbuf[jb * 64 + row];
        lv[c2] = lbuf[jb * 64 + row];
        M = fmaxf(M, mv[c2]);
    }
    float L = 0.f;
    for (int c2 = 0; c2 < nc; ++c2) L += __expf(mv[c2] - M) * lv[c2];
    const float Linv = 1.0f / L;

    float acc[32];
#pragma unroll
    for (int i = 0; i < 32; ++i) acc[i] = 0.f;
    for (int c2 = 0; c2 < nc; ++c2) {
        const float wgt = __expf(mv[c2] - M) * Linv;
        const unsigned short* po = Opart + ((size_t)b * NJOBS + j0 + c2) * (64 * 128) +
                                   (size_t)row * 128 + cg;
#pragma unroll
        for (int i = 0; i < 4; ++i) {
            i32x4 d = *(const i32x4*)&po[i * 8];
#pragma unroll
            for (int e = 0; e < 4; ++e) {
                unsigned int u = (unsigned int)d[e];
                acc[i * 8 + e * 2]     = fmaf(wgt, bf2f((unsigned short)(u & 0xffff)), acc[i * 8 + e * 2]);
                acc[i * 8 + e * 2 + 1] = fmaf(wgt, bf2f((unsigned short)(u >> 16)),   acc[i * 8 + e * 2 + 1]);
            }
        }
    }
    float* op = out + ((size_t)b * SEQ + qi * 64 + row) * HD + cg;
#pragma unroll
    for (int i = 0; i < 8; ++i) {
        float4 res;
        res.x = acc[i * 4]; res.y = acc[i * 4 + 1];
        res.z = acc[i * 4 + 2]; res.w = acc[i * 4 + 3];
        *(float4*)&op[i * 4] = res;
    }
}

extern "C" void kernel_launch(void* const* d_in, const int* in_sizes, int n_in,
                              void* d_out, int out_size, void* d_ws, size_t ws_size,
                              hipStream_t stream) {
    const float* x  = (const float*)d_in[0];
    const float* Wq = (const float*)d_in[1];
    const float* Wk = (const float*)d_in[2];
    const float* Wv = (const float*)d_in[3];

    unsigned short* qb    = (unsigned short*)d_ws;          // [16384][128] bf16
    unsigned short* kb    = qb  + (size_t)MROWS * HD;       // [16384][128] bf16
    unsigned short* vtb   = kb  + (size_t)MROWS * HD;       // [4][128][4096] bf16
    unsigned short* Wt    = vtb + (size_t)MROWS * HD;       // [3][128][1024] bf16
    unsigned short* Opart = Wt  + (size_t)3 * HD * EMB;     // [4][204][64][128] bf16
    float* mbuf = (float*)(Opart + (size_t)BATCH * NJOBS * 64 * 128);
    float* lbuf = mbuf + (size_t)BATCH * NJOBS * 64;
    float* out = (float*)d_out;

    wtrans_kernel <<<dim3(16, 3),    dim3(128), 0, stream>>>(Wq, Wk, Wv, Wt);
    qkv_kernel    <<<dim3(3, 256),   dim3(256), 0, stream>>>(x, Wt, qb, kb, vtb);
    flash_kernel  <<<dim3(NJOBS, 4), dim3(256), 0, stream>>>(qb, kb, vtb, Opart, mbuf, lbuf);
    combine_kernel<<<dim3(64, 4),    dim3(256), 0, stream>>>(Opart, mbuf, lbuf, out);
}

// Round 5
// 246.368 us; speedup vs baseline: 1.1300x; 1.1300x over previous
//
#include <hip/hip_runtime.h>
#include <math.h>

#define BATCH 4
#define SEQ   4096
#define EMB   1024
#define HD    128
#define MROWS (BATCH*SEQ)
#define SCALE 0.08838834764831844f   // 1/sqrt(128)
#define NJOBS 204                    // split-KV jobs per batch (BQ=64, chunk=12 kv-tiles)
#define MAXC  6

typedef __attribute__((ext_vector_type(8))) short bf16x8;   // MFMA A/B frag (4 VGPR)
typedef __attribute__((ext_vector_type(4))) short short4v;  // 8B LDS store
typedef __attribute__((ext_vector_type(4))) float f32x4;    // MFMA C/D frag
typedef __attribute__((ext_vector_type(4))) int   i32x4;    // 16B copy

static __device__ __forceinline__ unsigned short f2bf(float f) {
    unsigned int u = __float_as_uint(f);
    u += 0x7fff + ((u >> 16) & 1);       // RNE
    return (unsigned short)(u >> 16);
}
static __device__ __forceinline__ float bf2f(unsigned short s) {
    return __uint_as_float((unsigned int)s << 16);
}

// ---------------- W transpose + bf16 (+ fold q-scale) ----------------
__global__ __launch_bounds__(128) void wtrans_kernel(
    const float* __restrict__ Wq, const float* __restrict__ Wk,
    const float* __restrict__ Wv, unsigned short* __restrict__ Wt)
{
    const int w  = blockIdx.y;
    const float* W = (w == 0) ? Wq : (w == 1) ? Wk : Wv;
    const float sc = (w == 0) ? SCALE : 1.0f;
    unsigned short* dst = Wt + (size_t)w * 131072;
    const int n  = threadIdx.x;
    const int k0 = blockIdx.x * 64;
    for (int jc = 0; jc < 8; ++jc) {
        i32x4 p;
#pragma unroll
        for (int e = 0; e < 4; ++e) {
            float lo = W[(size_t)(k0 + jc * 8 + e * 2)     * HD + n] * sc;
            float hi = W[(size_t)(k0 + jc * 8 + e * 2 + 1) * HD + n] * sc;
            p[e] = (unsigned int)f2bf(lo) | ((unsigned int)f2bf(hi) << 16);
        }
        *(i32x4*)&dst[(size_t)n * 1024 + k0 + jc * 8] = p;
    }
}

// ---------------- Fused QKV projection: read x ONCE, all 384 cols ----------------
// grid 512 blocks (32 m-rows each), 512 thr = 8 waves.
// Wave w: m-tile mh=w&1 (16 rows), n-group ng=w>>1 -> 6 n-tiles nt = ng+4j (j=0..5).
// nt 0-7 -> q, 8-15 -> k, 16-23 -> v.  A staged in LDS (fp32->bf16); B direct from
// L2-resident Wt. acc = 6 f32x4 per lane.
__global__ __launch_bounds__(512, 2) void qkv_kernel(
    const float* __restrict__ x, const unsigned short* __restrict__ Wt,
    unsigned short* __restrict__ qb, unsigned short* __restrict__ kb,
    unsigned short* __restrict__ vtb)
{
    __shared__ __align__(16) unsigned short lds[128 * 40];   // 10.2 KB (union of 3 uses)

    const int t    = threadIdx.x;
    const int lane = t & 63, w = t >> 6;
    const int quad = lane >> 4, l16 = lane & 15;
    const int mh   = w & 1;
    const int ng   = w >> 1;
    const int m0   = blockIdx.x * 32;

    f32x4 acc[6];
#pragma unroll
    for (int j = 0; j < 6; ++j) acc[j] = (f32x4){0.f, 0.f, 0.f, 0.f};

    const int xrow = t >> 4, xseg = t & 15;   // 16 thr/row, float4 each

    for (int kt = 0; kt < EMB; kt += 64) {
        __syncthreads();
        float4 xa = *(const float4*)&x[(size_t)(m0 + xrow) * EMB + kt + xseg * 4];
        short4v xc;
        xc[0] = (short)f2bf(xa.x); xc[1] = (short)f2bf(xa.y);
        xc[2] = (short)f2bf(xa.z); xc[3] = (short)f2bf(xa.w);
        *(short4v*)&lds[xrow * 72 + xseg * 4] = xc;
        __syncthreads();
#pragma unroll
        for (int ks = 0; ks < 2; ++ks) {
            bf16x8 aA = *(const bf16x8*)&lds[(mh * 16 + l16) * 72 + ks * 32 + quad * 8];
#pragma unroll
            for (int j = 0; j < 6; ++j) {
                int nt = ng + 4 * j;
                int wm = nt >> 3, nl = nt & 7;
                bf16x8 aB = *(const bf16x8*)&Wt[(size_t)wm * 131072 +
                                                (size_t)(nl * 16 + l16) * 1024 +
                                                kt + ks * 32 + quad * 8];
                acc[j] = __builtin_amdgcn_mfma_f32_16x16x32_bf16(aA, aB, acc[j], 0, 0, 0);
            }
        }
    }

    // ---- epilogue: per-matrix LDS bounce, coalesced copy out ----
#pragma unroll
    for (int wm = 0; wm < 3; ++wm) {
        __syncthreads();
        if (wm < 2) {
            // natural [s][h], 32 x 136 pad
#pragma unroll
            for (int jj = 0; jj < 2; ++jj) {
                int j = 2 * wm + jj;
                int ncol = ng * 16 + jj * 64;
#pragma unroll
                for (int rr = 0; rr < 4; ++rr)
                    lds[(mh * 16 + quad * 4 + rr) * 136 + ncol + l16] = f2bf(acc[j][rr]);
            }
            __syncthreads();
            unsigned short* dst = ((wm == 0) ? qb : kb) + (size_t)m0 * HD;
            int row = t >> 4, seg = t & 15;     // 512 i32x4, one per thread
            *(i32x4*)&dst[(size_t)row * HD + seg * 8] = *(const i32x4*)&lds[row * 136 + seg * 8];
        } else {
            // transposed [h][s=32], 128 x 40 pad
#pragma unroll
            for (int jj = 0; jj < 2; ++jj) {
                int j = 4 + jj;
                int ncol = ng * 16 + jj * 64;
                short4v p;
                p[0] = (short)f2bf(acc[j][0]); p[1] = (short)f2bf(acc[j][1]);
                p[2] = (short)f2bf(acc[j][2]); p[3] = (short)f2bf(acc[j][3]);
                *(short4v*)&lds[(ncol + l16) * 40 + mh * 16 + quad * 4] = p;
            }
            __syncthreads();
            const int b = m0 >> 12, s0 = m0 & 4095;
            int h = t >> 2, seg = t & 3;        // 512 i32x4, one per thread
            *(i32x4*)&vtb[(size_t)b * (HD * SEQ) + (size_t)h * SEQ + s0 + seg * 8] =
                *(const i32x4*)&lds[h * 40 + seg * 8];
        }
    }
}

// ---------------- Flash attention: split-KV, BQ=64, LDS K/V staging ----------------
// Job = (b, qi 64-row tile, chunk c of 12 kv-tiles). grid (204, 4), 256 thr = 4 waves.
// R3-proven loop structure; 4 waves share one staged K/V copy.
#define PADK 136
#define PADV 72
#define PADP 72

__global__ __launch_bounds__(256, 3) void flash_kernel(
    const unsigned short* __restrict__ qb, const unsigned short* __restrict__ kb,
    const unsigned short* __restrict__ vtb, unsigned short* __restrict__ Opart,
    float* __restrict__ mbuf, float* __restrict__ lbuf)
{
    __shared__ __align__(16) unsigned short Ks[64 * PADK];    // 17.4 KB
    __shared__ __align__(16) unsigned short Vt[128 * PADV];   // 18.4 KB
    __shared__ __align__(16) unsigned short Pt[64 * PADP];    //  9.2 KB

    const int t    = threadIdx.x;
    const int lane = t & 63, w = t >> 6;
    const int quad = lane >> 4, l16 = lane & 15;
    const int b    = blockIdx.y;

    // decode job j -> (qi, c): group g = qi/12 has chunk-count g+1
    const int j = blockIdx.x;
    int g = 0, s = 0;
#pragma unroll
    for (int gg = 0; gg < 5; ++gg)
        if (j >= s + 12 * (g + 1)) { s += 12 * (g + 1); ++g; }
    const int idx = j - s;
    const int qi  = 12 * g + idx / (g + 1);
    const int c   = idx % (g + 1);

    const int qrow = qi * 64 + w * 16 + l16;
    const int jbeg = c * 12;
    const int jend = min(jbeg + 12, qi + 1);

    bf16x8 qf[4];
    {
        const unsigned short* qp = qb + ((size_t)b * SEQ + qrow) * HD;
#pragma unroll
        for (int ks = 0; ks < 4; ++ks)
            qf[ks] = *(const bf16x8*)&qp[ks * 32 + quad * 8];
    }

    f32x4 O[8];
#pragma unroll
    for (int i = 0; i < 8; ++i) O[i] = (f32x4){0.f, 0.f, 0.f, 0.f};
    float m_run = -1e30f, l_run = 0.f;

    const unsigned short* kbb  = kb  + (size_t)b * SEQ * HD;
    const unsigned short* vtbb = vtb + (size_t)b * HD * SEQ;

    for (int j0 = jbeg; j0 < jend; ++j0) {
        __syncthreads();   // prior iteration's reads of Ks/Vt complete
        // stage K tile 64x128 (16 KB contiguous)
#pragma unroll
        for (int i = 0; i < 4; ++i) {
            int gg = i * 256 + t;
            i32x4 kd = *(const i32x4*)&kbb[(size_t)j0 * 64 * HD + (size_t)gg * 8];
            *(i32x4*)&Ks[(gg >> 4) * PADK + (gg & 15) * 8] = kd;
        }
        // stage V^T tile 128x64
#pragma unroll
        for (int i = 0; i < 4; ++i) {
            int gg = i * 256 + t;
            i32x4 vd = *(const i32x4*)&vtbb[(size_t)(gg >> 3) * SEQ + j0 * 64 + (gg & 7) * 8];
            *(i32x4*)&Vt[(gg >> 3) * PADV + (gg & 7) * 8] = vd;
        }
        __syncthreads();

        // ---- S^T = K . Q^T ----
        f32x4 st[4];
#pragma unroll
        for (int mt = 0; mt < 4; ++mt) {
            f32x4 a = (f32x4){0.f, 0.f, 0.f, 0.f};
#pragma unroll
            for (int ks = 0; ks < 4; ++ks) {
                bf16x8 kf = *(const bf16x8*)&Ks[(mt * 16 + l16) * PADK + ks * 32 + quad * 8];
                a = __builtin_amdgcn_mfma_f32_16x16x32_bf16(kf, qf[ks], a, 0, 0, 0);
            }
            st[mt] = a;
        }

        // ---- causal mask (wave-uniform skip when tile fully valid) ----
        if (j0 * 64 + 63 > qi * 64 + w * 16) {
#pragma unroll
            for (int mt = 0; mt < 4; ++mt)
#pragma unroll
                for (int rr = 0; rr < 4; ++rr) {
                    int kv = j0 * 64 + mt * 16 + quad * 4 + rr;
                    if (kv > qrow) st[mt][rr] = -1e30f;
                }
        }

        // ---- online softmax (lane owns one q-row) ----
        float mx = -1e30f;
#pragma unroll
        for (int mt = 0; mt < 4; ++mt)
#pragma unroll
            for (int rr = 0; rr < 4; ++rr) mx = fmaxf(mx, st[mt][rr]);
        mx = fmaxf(mx, __shfl_xor(mx, 16));
        mx = fmaxf(mx, __shfl_xor(mx, 32));
        const float m_new = fmaxf(m_run, mx);
        const float alpha = __expf(m_run - m_new);
        float psum = 0.f;
#pragma unroll
        for (int mt = 0; mt < 4; ++mt)
#pragma unroll
            for (int rr = 0; rr < 4; ++rr) {
                float p = __expf(st[mt][rr] - m_new);
                st[mt][rr] = p;
                psum += p;
            }
        psum += __shfl_xor(psum, 16);
        psum += __shfl_xor(psum, 32);
        m_run = m_new;
        l_run = l_run * alpha + psum;

        // ---- P^T -> LDS (wave-private rows; no barrier needed) ----
#pragma unroll
        for (int mt = 0; mt < 4; ++mt) {
            short4v p;
            p[0] = (short)f2bf(st[mt][0]); p[1] = (short)f2bf(st[mt][1]);
            p[2] = (short)f2bf(st[mt][2]); p[3] = (short)f2bf(st[mt][3]);
            *(short4v*)&Pt[(w * 16 + l16) * PADP + mt * 16 + quad * 4] = p;
        }

#pragma unroll
        for (int i = 0; i < 8; ++i) {
            O[i][0] *= alpha; O[i][1] *= alpha; O[i][2] *= alpha; O[i][3] *= alpha;
        }

        // ---- O^T += V^T . P^T ----
        bf16x8 pf0 = *(const bf16x8*)&Pt[(w * 16 + l16) * PADP + quad * 8];
        bf16x8 pf1 = *(const bf16x8*)&Pt[(w * 16 + l16) * PADP + 32 + quad * 8];
#pragma unroll
        for (int mt = 0; mt < 8; ++mt) {
            bf16x8 vf0 = *(const bf16x8*)&Vt[(mt * 16 + l16) * PADV + quad * 8];
            bf16x8 vf1 = *(const bf16x8*)&Vt[(mt * 16 + l16) * PADV + 32 + quad * 8];
            O[mt] = __builtin_amdgcn_mfma_f32_16x16x32_bf16(vf0, pf0, O[mt], 0, 0, 0);
            O[mt] = __builtin_amdgcn_mfma_f32_16x16x32_bf16(vf1, pf1, O[mt], 0, 0, 0);
        }
    }

    // ---- partial epilogue: unnormalized O (bf16) + m,l ----
    const int r = w * 16 + l16;
    const size_t jobbase = (size_t)b * NJOBS + j;
    unsigned short* po = Opart + jobbase * (64 * 128) + (size_t)r * 128;
#pragma unroll
    for (int mt = 0; mt < 8; ++mt) {
        short4v p;
        p[0] = (short)f2bf(O[mt][0]); p[1] = (short)f2bf(O[mt][1]);
        p[2] = (short)f2bf(O[mt][2]); p[3] = (short)f2bf(O[mt][3]);
        *(short4v*)&po[mt * 16 + quad * 4] = p;
    }
    if (quad == 0) {
        mbuf[jobbase * 64 + r] = m_run;
        lbuf[jobbase * 64 + r] = l_run;
    }
}

// ---------------- Combine partials ----------------
// grid (64, 4), 256 thr: thread -> q-row t>>2, 32 head cols at (t&3)*32.
__global__ __launch_bounds__(256) void combine_kernel(
    const unsigned short* __restrict__ Opart, const float* __restrict__ mbuf,
    const float* __restrict__ lbuf, float* __restrict__ out)
{
    const int qi = blockIdx.x, b = blockIdx.y;
    const int g  = qi / 12;
    const int nc = g + 1;
    const int j0 = 6 * g * (g + 1) + (qi - 12 * g) * (g + 1);
    const int t = threadIdx.x;
    const int row = t >> 2, cg = (t & 3) * 32;

    float mv[MAXC], lv[MAXC];
    float M = -1e30f;
    for (int c2 = 0; c2 < nc; ++c2) {
        const size_t jb = (size_t)b * NJOBS + j0 + c2;
        mv[c2] = mbuf[jb * 64 + row];
        lv[c2] = lbuf[jb * 64 + row];
        M = fmaxf(M, mv[c2]);
    }
    float L = 0.f;
    for (int c2 = 0; c2 < nc; ++c2) L += __expf(mv[c2] - M) * lv[c2];
    const float Linv = 1.0f / L;

    float acc[32];
#pragma unroll
    for (int i = 0; i < 32; ++i) acc[i] = 0.f;
    for (int c2 = 0; c2 < nc; ++c2) {
        const float wgt = __expf(mv[c2] - M) * Linv;
        const unsigned short* po = Opart + ((size_t)b * NJOBS + j0 + c2) * (64 * 128) +
                                   (size_t)row * 128 + cg;
#pragma unroll
        for (int i = 0; i < 4; ++i) {
            i32x4 d = *(const i32x4*)&po[i * 8];
#pragma unroll
            for (int e = 0; e < 4; ++e) {
                unsigned int u = (unsigned int)d[e];
                acc[i * 8 + e * 2]     = fmaf(wgt, bf2f((unsigned short)(u & 0xffff)), acc[i * 8 + e * 2]);
                acc[i * 8 + e * 2 + 1] = fmaf(wgt, bf2f((unsigned short)(u >> 16)),   acc[i * 8 + e * 2 + 1]);
            }
        }
    }
    float* op = out + ((size_t)b * SEQ + qi * 64 + row) * HD + cg;
#pragma unroll
    for (int i = 0; i < 8; ++i) {
        float4 res;
        res.x = acc[i * 4]; res.y = acc[i * 4 + 1];
        res.z = acc[i * 4 + 2]; res.w = acc[i * 4 + 3];
        *(float4*)&op[i * 4] = res;
    }
}

extern "C" void kernel_launch(void* const* d_in, const int* in_sizes, int n_in,
                              void* d_out, int out_size, void* d_ws, size_t ws_size,
                              hipStream_t stream) {
    const float* x  = (const float*)d_in[0];
    const float* Wq = (const float*)d_in[1];
    const float* Wk = (const float*)d_in[2];
    const float* Wv = (const float*)d_in[3];

    unsigned short* qb    = (unsigned short*)d_ws;          // [16384][128] bf16
    unsigned short* kb    = qb  + (size_t)MROWS * HD;       // [16384][128] bf16
    unsigned short* vtb   = kb  + (size_t)MROWS * HD;       // [4][128][4096] bf16
    unsigned short* Wt    = vtb + (size_t)MROWS * HD;       // [3][128][1024] bf16
    unsigned short* Opart = Wt  + (size_t)3 * HD * EMB;     // [4][204][64][128] bf16
    float* mbuf = (float*)(Opart + (size_t)BATCH * NJOBS * 64 * 128);
    float* lbuf = mbuf + (size_t)BATCH * NJOBS * 64;
    float* out = (float*)d_out;

    wtrans_kernel <<<dim3(16, 3),    dim3(128), 0, stream>>>(Wq, Wk, Wv, Wt);
    qkv_kernel    <<<dim3(512),      dim3(512), 0, stream>>>(x, Wt, qb, kb, vtb);
    flash_kernel  <<<dim3(NJOBS, 4), dim3(256), 0, stream>>>(qb, kb, vtb, Opart, mbuf, lbuf);
    combine_kernel<<<dim3(64, 4),    dim3(256), 0, stream>>>(Opart, mbuf, lbuf, out);
}

// Round 6
// 186.680 us; speedup vs baseline: 1.4913x; 1.3197x over previous
//
#include <hip/hip_runtime.h>
#include <math.h>

#define BATCH 4
#define SEQ   4096
#define EMB   1024
#define HD    128
#define MROWS (BATCH*SEQ)
#define SCALE 0.08838834764831844f   // 1/sqrt(128)
#define NJOBS 204                    // split-KV jobs per batch (BQ=64, chunk=12 kv-tiles)
#define MAXC  6

typedef __attribute__((ext_vector_type(8))) short bf16x8;   // MFMA A/B frag (4 VGPR)
typedef __attribute__((ext_vector_type(4))) short short4v;  // 8B LDS store
typedef __attribute__((ext_vector_type(4))) float f32x4;    // MFMA C/D frag
typedef __attribute__((ext_vector_type(4))) int   i32x4;    // 16B copy

static __device__ __forceinline__ unsigned short f2bf(float f) {
    unsigned int u = __float_as_uint(f);
    u += 0x7fff + ((u >> 16) & 1);       // RNE
    return (unsigned short)(u >> 16);
}
static __device__ __forceinline__ float bf2f(unsigned short s) {
    return __uint_as_float((unsigned int)s << 16);
}

// ---------------- W transpose + bf16 (+ fold q-scale) ----------------
__global__ __launch_bounds__(128) void wtrans_kernel(
    const float* __restrict__ Wq, const float* __restrict__ Wk,
    const float* __restrict__ Wv, unsigned short* __restrict__ Wt)
{
    const int w  = blockIdx.y;
    const float* W = (w == 0) ? Wq : (w == 1) ? Wk : Wv;
    const float sc = (w == 0) ? SCALE : 1.0f;
    unsigned short* dst = Wt + (size_t)w * 131072;
    const int n  = threadIdx.x;
    const int k0 = blockIdx.x * 64;
    for (int jc = 0; jc < 8; ++jc) {
        i32x4 p;
#pragma unroll
        for (int e = 0; e < 4; ++e) {
            float lo = W[(size_t)(k0 + jc * 8 + e * 2)     * HD + n] * sc;
            float hi = W[(size_t)(k0 + jc * 8 + e * 2 + 1) * HD + n] * sc;
            p[e] = (unsigned int)f2bf(lo) | ((unsigned int)f2bf(hi) << 16);
        }
        *(i32x4*)&dst[(size_t)n * 1024 + k0 + jc * 8] = p;
    }
}

// ---------------- Fused QKV projection: read x ONCE, W staged in LDS ----------------
// grid 512 blocks (32 m-rows each), 512 thr = 8 waves.
// Wave ng = w owns n-tiles nt = 3*ng + {0,1,2} (24 tiles of 16 = 384 cols = q|k|v),
// and both m-tiles (32 rows). W tile [384][64] + x tile [32][64] staged in LDS per
// kt step -> each Wt line fetched ONCE per block (kills the R5 L2 hot-line storm).
__global__ __launch_bounds__(512, 4) void qkv_kernel(
    const float* __restrict__ x, const unsigned short* __restrict__ Wt,
    unsigned short* __restrict__ qb, unsigned short* __restrict__ kb,
    unsigned short* __restrict__ vtb)
{
    __shared__ __align__(16) unsigned short lds[32 * 72 + 384 * 72];   // 59.9 KB
    unsigned short* xs = lds;              // x tile  32(m) x 64(k), pad 72
    unsigned short* Ws = lds + 32 * 72;    // W tile 384(n) x 64(k), pad 72

    const int t    = threadIdx.x;
    const int lane = t & 63, ng = t >> 6;
    const int quad = lane >> 4, l16 = lane & 15;
    const int m0   = blockIdx.x * 32;

    f32x4 acc[2][3];
#pragma unroll
    for (int i = 0; i < 2; ++i)
#pragma unroll
        for (int j = 0; j < 3; ++j) acc[i][j] = (f32x4){0.f, 0.f, 0.f, 0.f};

    const int xrow = t >> 4, xc4 = t & 15;    // x: one float4 per thread per kt
    const int wrow = t >> 3, wseg = t & 7;    // W: rows via g = i*512+t

    for (int kt = 0; kt < EMB; kt += 64) {
        __syncthreads();
        // stage x fp32 -> bf16 (32 x 64)
        {
            float4 xa = *(const float4*)&x[(size_t)(m0 + xrow) * EMB + kt + xc4 * 4];
            short4v xcv;
            xcv[0] = (short)f2bf(xa.x); xcv[1] = (short)f2bf(xa.y);
            xcv[2] = (short)f2bf(xa.z); xcv[3] = (short)f2bf(xa.w);
            *(short4v*)&xs[xrow * 72 + xc4 * 4] = xcv;
        }
        // stage W bf16 (384 x 64), coalesced b128
#pragma unroll
        for (int i = 0; i < 6; ++i) {
            int row = i * 64 + wrow;
            *(i32x4*)&Ws[row * 72 + wseg * 8] =
                *(const i32x4*)&Wt[(size_t)row * 1024 + kt + wseg * 8];
        }
        __syncthreads();
#pragma unroll
        for (int ks = 0; ks < 2; ++ks) {
            bf16x8 aA[2], aB[3];
#pragma unroll
            for (int mt = 0; mt < 2; ++mt)
                aA[mt] = *(const bf16x8*)&xs[(mt * 16 + l16) * 72 + ks * 32 + quad * 8];
#pragma unroll
            for (int jt = 0; jt < 3; ++jt)
                aB[jt] = *(const bf16x8*)&Ws[((ng * 3 + jt) * 16 + l16) * 72 + ks * 32 + quad * 8];
#pragma unroll
            for (int mt = 0; mt < 2; ++mt)
#pragma unroll
                for (int jt = 0; jt < 3; ++jt)
                    acc[mt][jt] = __builtin_amdgcn_mfma_f32_16x16x32_bf16(
                        aA[mt], aB[jt], acc[mt][jt], 0, 0, 0);
        }
    }

    // ---- epilogue: scatter to LDS (per-matrix layout), then coalesced copy out ----
    __syncthreads();
    unsigned short* Cq = lds;                 // [32][136]
    unsigned short* Ck = lds + 32 * 136;      // [32][136]
    unsigned short* Cv = lds + 2 * 32 * 136;  // [128][40] (transposed)
#pragma unroll
    for (int mt = 0; mt < 2; ++mt)
#pragma unroll
        for (int jt = 0; jt < 3; ++jt) {
            int nt = ng * 3 + jt;
            int wm = nt >> 3, nl = nt & 7;
            if (wm < 2) {
                unsigned short* C = (wm == 0) ? Cq : Ck;
#pragma unroll
                for (int rr = 0; rr < 4; ++rr)
                    C[(mt * 16 + quad * 4 + rr) * 136 + nl * 16 + l16] =
                        f2bf(acc[mt][jt][rr]);
            } else {
                short4v p;
                p[0] = (short)f2bf(acc[mt][jt][0]); p[1] = (short)f2bf(acc[mt][jt][1]);
                p[2] = (short)f2bf(acc[mt][jt][2]); p[3] = (short)f2bf(acc[mt][jt][3]);
                *(short4v*)&Cv[(nl * 16 + l16) * 40 + mt * 16 + quad * 4] = p;
            }
        }
    __syncthreads();
    {   // q, k: 32 x 128 each -> 512 i32x4, one per thread
        int row = t >> 4, seg = t & 15;
        *(i32x4*)&qb[((size_t)(m0 + row)) * HD + seg * 8] = *(const i32x4*)&Cq[row * 136 + seg * 8];
        *(i32x4*)&kb[((size_t)(m0 + row)) * HD + seg * 8] = *(const i32x4*)&Ck[row * 136 + seg * 8];
    }
    {   // v^T: 128 x 32 -> 512 i32x4, one per thread
        const int b = m0 >> 12, s0 = m0 & 4095;
        int h = t >> 2, seg = t & 3;
        *(i32x4*)&vtb[(size_t)b * (HD * SEQ) + (size_t)h * SEQ + s0 + seg * 8] =
            *(const i32x4*)&Cv[h * 40 + seg * 8];
    }
}

// ---------------- Flash attention: split-KV, BQ=64, LDS K/V staging ----------------
// Job = (b, qi 64-row tile, chunk c of 12 kv-tiles). grid (204, 4), 256 thr = 4 waves.
#define PADK 136
#define PADV 72
#define PADP 72

__global__ __launch_bounds__(256, 3) void flash_kernel(
    const unsigned short* __restrict__ qb, const unsigned short* __restrict__ kb,
    const unsigned short* __restrict__ vtb, unsigned short* __restrict__ Opart,
    float* __restrict__ mbuf, float* __restrict__ lbuf)
{
    __shared__ __align__(16) unsigned short Ks[64 * PADK];    // 17.4 KB
    __shared__ __align__(16) unsigned short Vt[128 * PADV];   // 18.4 KB
    __shared__ __align__(16) unsigned short Pt[64 * PADP];    //  9.2 KB

    const int t    = threadIdx.x;
    const int lane = t & 63, w = t >> 6;
    const int quad = lane >> 4, l16 = lane & 15;
    const int b    = blockIdx.y;

    // decode job j -> (qi, c): group g = qi/12 has chunk-count g+1
    const int j = blockIdx.x;
    int g = 0, s = 0;
#pragma unroll
    for (int gg = 0; gg < 5; ++gg)
        if (j >= s + 12 * (g + 1)) { s += 12 * (g + 1); ++g; }
    const int idx = j - s;
    const int qi  = 12 * g + idx / (g + 1);
    const int c   = idx % (g + 1);

    const int qrow = qi * 64 + w * 16 + l16;
    const int jbeg = c * 12;
    const int jend = min(jbeg + 12, qi + 1);

    bf16x8 qf[4];
    {
        const unsigned short* qp = qb + ((size_t)b * SEQ + qrow) * HD;
#pragma unroll
        for (int ks = 0; ks < 4; ++ks)
            qf[ks] = *(const bf16x8*)&qp[ks * 32 + quad * 8];
    }

    f32x4 O[8];
#pragma unroll
    for (int i = 0; i < 8; ++i) O[i] = (f32x4){0.f, 0.f, 0.f, 0.f};
    float m_run = -1e30f, l_run = 0.f;

    const unsigned short* kbb  = kb  + (size_t)b * SEQ * HD;
    const unsigned short* vtbb = vtb + (size_t)b * HD * SEQ;

    for (int j0 = jbeg; j0 < jend; ++j0) {
        __syncthreads();   // prior iteration's reads of Ks/Vt complete
#pragma unroll
        for (int i = 0; i < 4; ++i) {
            int gg = i * 256 + t;
            i32x4 kd = *(const i32x4*)&kbb[(size_t)j0 * 64 * HD + (size_t)gg * 8];
            *(i32x4*)&Ks[(gg >> 4) * PADK + (gg & 15) * 8] = kd;
        }
#pragma unroll
        for (int i = 0; i < 4; ++i) {
            int gg = i * 256 + t;
            i32x4 vd = *(const i32x4*)&vtbb[(size_t)(gg >> 3) * SEQ + j0 * 64 + (gg & 7) * 8];
            *(i32x4*)&Vt[(gg >> 3) * PADV + (gg & 7) * 8] = vd;
        }
        __syncthreads();

        // ---- S^T = K . Q^T ----
        f32x4 st[4];
#pragma unroll
        for (int mt = 0; mt < 4; ++mt) {
            f32x4 a = (f32x4){0.f, 0.f, 0.f, 0.f};
#pragma unroll
            for (int ks = 0; ks < 4; ++ks) {
                bf16x8 kf = *(const bf16x8*)&Ks[(mt * 16 + l16) * PADK + ks * 32 + quad * 8];
                a = __builtin_amdgcn_mfma_f32_16x16x32_bf16(kf, qf[ks], a, 0, 0, 0);
            }
            st[mt] = a;
        }

        // ---- causal mask (wave-uniform skip when tile fully valid) ----
        if (j0 * 64 + 63 > qi * 64 + w * 16) {
#pragma unroll
            for (int mt = 0; mt < 4; ++mt)
#pragma unroll
                for (int rr = 0; rr < 4; ++rr) {
                    int kv = j0 * 64 + mt * 16 + quad * 4 + rr;
                    if (kv > qrow) st[mt][rr] = -1e30f;
                }
        }

        // ---- online softmax (lane owns one q-row) ----
        float mx = -1e30f;
#pragma unroll
        for (int mt = 0; mt < 4; ++mt)
#pragma unroll
            for (int rr = 0; rr < 4; ++rr) mx = fmaxf(mx, st[mt][rr]);
        mx = fmaxf(mx, __shfl_xor(mx, 16));
        mx = fmaxf(mx, __shfl_xor(mx, 32));
        const float m_new = fmaxf(m_run, mx);
        const float alpha = __expf(m_run - m_new);
        float psum = 0.f;
#pragma unroll
        for (int mt = 0; mt < 4; ++mt)
#pragma unroll
            for (int rr = 0; rr < 4; ++rr) {
                float p = __expf(st[mt][rr] - m_new);
                st[mt][rr] = p;
                psum += p;
            }
        psum += __shfl_xor(psum, 16);
        psum += __shfl_xor(psum, 32);
        m_run = m_new;
        l_run = l_run * alpha + psum;

        // ---- P^T -> LDS (wave-private rows; no barrier needed) ----
#pragma unroll
        for (int mt = 0; mt < 4; ++mt) {
            short4v p;
            p[0] = (short)f2bf(st[mt][0]); p[1] = (short)f2bf(st[mt][1]);
            p[2] = (short)f2bf(st[mt][2]); p[3] = (short)f2bf(st[mt][3]);
            *(short4v*)&Pt[(w * 16 + l16) * PADP + mt * 16 + quad * 4] = p;
        }

#pragma unroll
        for (int i = 0; i < 8; ++i) {
            O[i][0] *= alpha; O[i][1] *= alpha; O[i][2] *= alpha; O[i][3] *= alpha;
        }

        // ---- O^T += V^T . P^T ----
        bf16x8 pf0 = *(const bf16x8*)&Pt[(w * 16 + l16) * PADP + quad * 8];
        bf16x8 pf1 = *(const bf16x8*)&Pt[(w * 16 + l16) * PADP + 32 + quad * 8];
#pragma unroll
        for (int mt = 0; mt < 8; ++mt) {
            bf16x8 vf0 = *(const bf16x8*)&Vt[(mt * 16 + l16) * PADV + quad * 8];
            bf16x8 vf1 = *(const bf16x8*)&Vt[(mt * 16 + l16) * PADV + 32 + quad * 8];
            O[mt] = __builtin_amdgcn_mfma_f32_16x16x32_bf16(vf0, pf0, O[mt], 0, 0, 0);
            O[mt] = __builtin_amdgcn_mfma_f32_16x16x32_bf16(vf1, pf1, O[mt], 0, 0, 0);
        }
    }

    // ---- partial epilogue: unnormalized O (bf16) + m,l ----
    const int r = w * 16 + l16;
    const size_t jobbase = (size_t)b * NJOBS + j;
    unsigned short* po = Opart + jobbase * (64 * 128) + (size_t)r * 128;
#pragma unroll
    for (int mt = 0; mt < 8; ++mt) {
        short4v p;
        p[0] = (short)f2bf(O[mt][0]); p[1] = (short)f2bf(O[mt][1]);
        p[2] = (short)f2bf(O[mt][2]); p[3] = (short)f2bf(O[mt][3]);
        *(short4v*)&po[mt * 16 + quad * 4] = p;
    }
    if (quad == 0) {
        mbuf[jobbase * 64 + r] = m_run;
        lbuf[jobbase * 64 + r] = l_run;
    }
}

// ---------------- Combine partials ----------------
__global__ __launch_bounds__(256) void combine_kernel(
    const unsigned short* __restrict__ Opart, const float* __restrict__ mbuf,
    const float* __restrict__ lbuf, float* __restrict__ out)
{
    const int qi = blockIdx.x, b = blockIdx.y;
    const int g  = qi / 12;
    const int nc = g + 1;
    const int j0 = 6 * g * (g + 1) + (qi - 12 * g) * (g + 1);
    const int t = threadIdx.x;
    const int row = t >> 2, cg = (t & 3) * 32;

    float mv[MAXC], lv[MAXC];
    float M = -1e30f;
    for (int c2 = 0; c2 < nc; ++c2) {
        const size_t jb = (size_t)b * NJOBS + j0 + c2;
        mv[c2] = mbuf[jb * 64 + row];
        lv[c2] = lbuf[jb * 64 + row];
        M = fmaxf(M, mv[c2]);
    }
    float L = 0.f;
    for (int c2 = 0; c2 < nc; ++c2) L += __expf(mv[c2] - M) * lv[c2];
    const float Linv = 1.0f / L;

    float acc[32];
#pragma unroll
    for (int i = 0; i < 32; ++i) acc[i] = 0.f;
    for (int c2 = 0; c2 < nc; ++c2) {
        const float wgt = __expf(mv[c2] - M) * Linv;
        const unsigned short* po = Opart + ((size_t)b * NJOBS + j0 + c2) * (64 * 128) +
                                   (size_t)row * 128 + cg;
#pragma unroll
        for (int i = 0; i < 4; ++i) {
            i32x4 d = *(const i32x4*)&po[i * 8];
#pragma unroll
            for (int e = 0; e < 4; ++e) {
                unsigned int u = (unsigned int)d[e];
                acc[i * 8 + e * 2]     = fmaf(wgt, bf2f((unsigned short)(u & 0xffff)), acc[i * 8 + e * 2]);
                acc[i * 8 + e * 2 + 1] = fmaf(wgt, bf2f((unsigned short)(u >> 16)),   acc[i * 8 + e * 2 + 1]);
            }
        }
    }
    float* op = out + ((size_t)b * SEQ + qi * 64 + row) * HD + cg;
#pragma unroll
    for (int i = 0; i < 8; ++i) {
        float4 res;
        res.x = acc[i * 4]; res.y = acc[i * 4 + 1];
        res.z = acc[i * 4 + 2]; res.w = acc[i * 4 + 3];
        *(float4*)&op[i * 4] = res;
    }
}

extern "C" void kernel_launch(void* const* d_in, const int* in_sizes, int n_in,
                              void* d_out, int out_size, void* d_ws, size_t ws_size,
                              hipStream_t stream) {
    const float* x  = (const float*)d_in[0];
    const float* Wq = (const float*)d_in[1];
    const float* Wk = (const float*)d_in[2];
    const float* Wv = (const float*)d_in[3];

    unsigned short* qb    = (unsigned short*)d_ws;          // [16384][128] bf16
    unsigned short* kb    = qb  + (size_t)MROWS * HD;       // [16384][128] bf16
    unsigned short* vtb   = kb  + (size_t)MROWS * HD;       // [4][128][4096] bf16
    unsigned short* Wt    = vtb + (size_t)MROWS * HD;       // [3][128][1024] bf16
    unsigned short* Opart = Wt  + (size_t)3 * HD * EMB;     // [4][204][64][128] bf16
    float* mbuf = (float*)(Opart + (size_t)BATCH * NJOBS * 64 * 128);
    float* lbuf = mbuf + (size_t)BATCH * NJOBS * 64;
    float* out = (float*)d_out;

    wtrans_kernel <<<dim3(16, 3),    dim3(128), 0, stream>>>(Wq, Wk, Wv, Wt);
    qkv_kernel    <<<dim3(512),      dim3(512), 0, stream>>>(x, Wt, qb, kb, vtb);
    flash_kernel  <<<dim3(NJOBS, 4), dim3(256), 0, stream>>>(qb, kb, vtb, Opart, mbuf, lbuf);
    combine_kernel<<<dim3(64, 4),    dim3(256), 0, stream>>>(Opart, mbuf, lbuf, out);
}

// Round 7
// 167.773 us; speedup vs baseline: 1.6594x; 1.1127x over previous
//
#include <hip/hip_runtime.h>
#include <math.h>

#define BATCH 4
#define SEQ   4096
#define EMB   1024
#define HD    128
#define MROWS (BATCH*SEQ)
#define SCALE 0.08838834764831844f   // 1/sqrt(128)
#define CHUNK 10                     // kv-tiles (of 64) per split-KV job
#define NJOBS 119                    // jobs per batch at BQ=128, CHUNK=10
#define MAXC  7                      // max chunks per q-tile = ceil(64/10)

typedef __attribute__((ext_vector_type(8))) short bf16x8;   // MFMA A/B frag (4 VGPR)
typedef __attribute__((ext_vector_type(4))) short short4v;  // 8B LDS store
typedef __attribute__((ext_vector_type(4))) float f32x4;    // MFMA C/D frag
typedef __attribute__((ext_vector_type(4))) int   i32x4;    // 16B copy

static __device__ __forceinline__ unsigned short f2bf(float f) {
    unsigned int u = __float_as_uint(f);
    u += 0x7fff + ((u >> 16) & 1);       // RNE
    return (unsigned short)(u >> 16);
}
static __device__ __forceinline__ float bf2f(unsigned short s) {
    return __uint_as_float((unsigned int)s << 16);
}

// ---------------- W transpose + bf16 (+ fold q-scale) ----------------
// grid (64, 3) x 256 thr. Block: 16 k-rows x 128 n of one matrix, via LDS transpose.
__global__ __launch_bounds__(256) void wtrans_kernel(
    const float* __restrict__ Wq, const float* __restrict__ Wk,
    const float* __restrict__ Wv, unsigned short* __restrict__ Wt)
{
    __shared__ __align__(16) unsigned short Xs[16 * 132];
    const int w  = blockIdx.y;
    const float* W = (w == 0) ? Wq : (w == 1) ? Wk : Wv;
    const float sc = (w == 0) ? SCALE : 1.0f;
    unsigned short* dst = Wt + (size_t)w * 131072;
    const int k0 = blockIdx.x * 16;
    const int t  = threadIdx.x;

#pragma unroll
    for (int i = 0; i < 2; ++i) {
        int gg = i * 256 + t;                 // 0..511
        int row = gg >> 5, c4 = gg & 31;
        float4 a = *(const float4*)&W[(size_t)(k0 + row) * HD + c4 * 4];
        short4v p;
        p[0] = (short)f2bf(a.x * sc); p[1] = (short)f2bf(a.y * sc);
        p[2] = (short)f2bf(a.z * sc); p[3] = (short)f2bf(a.w * sc);
        *(short4v*)&Xs[row * 132 + c4 * 4] = p;
    }
    __syncthreads();
    const int n = t >> 1, half = t & 1;
    i32x4 o;
#pragma unroll
    for (int e = 0; e < 4; ++e) {
        unsigned int lo = Xs[(half * 8 + e * 2    ) * 132 + n];
        unsigned int hi = Xs[(half * 8 + e * 2 + 1) * 132 + n];
        o[e] = (int)(lo | (hi << 16));
    }
    *(i32x4*)&dst[(size_t)n * 1024 + k0 + half * 8] = o;
}

// ---------------- Fused QKV: read x once; wave-private W staging; x dbuf ----------------
// grid 512 x 512 thr (8 waves). Wave ng owns n-tiles 3ng..3ng+2 (48 W rows) and both
// 16-row m-tiles. W staged wave-private (no barrier); x double-buffered (1 barrier/kt).
__global__ __launch_bounds__(512, 4) void qkv_kernel(
    const float* __restrict__ x, const unsigned short* __restrict__ Wt,
    unsigned short* __restrict__ qb, unsigned short* __restrict__ kb,
    unsigned short* __restrict__ vtb)
{
    __shared__ __align__(16) unsigned short lds[2 * 2304 + 384 * 72];   // 64.5 KB
    unsigned short* xs0 = lds;           // x tile 32 x 64, pad 72 (buf 0)
    unsigned short* xs1 = lds + 2304;    // buf 1
    unsigned short* Ws  = lds + 4608;    // W tile 384 x 64, pad 72

    const int t    = threadIdx.x;
    const int lane = t & 63, ng = t >> 6;
    const int quad = lane >> 4, l16 = lane & 15;
    const int m0   = blockIdx.x * 32;

    f32x4 acc[2][3];
#pragma unroll
    for (int i = 0; i < 2; ++i)
#pragma unroll
        for (int j = 0; j < 3; ++j) acc[i][j] = (f32x4){0.f, 0.f, 0.f, 0.f};

    const int xrow = t >> 3, xseg = t & 7;   // staging threads t<256
    // prologue: stage x(kt=0)
    if (t < 256) {
        float4 a = *(const float4*)&x[(size_t)(m0 + xrow) * EMB + xseg * 8];
        float4 b2 = *(const float4*)&x[(size_t)(m0 + xrow) * EMB + xseg * 8 + 4];
        i32x4 p;
        p[0] = (int)((unsigned)f2bf(a.x) | ((unsigned)f2bf(a.y) << 16));
        p[1] = (int)((unsigned)f2bf(a.z) | ((unsigned)f2bf(a.w) << 16));
        p[2] = (int)((unsigned)f2bf(b2.x) | ((unsigned)f2bf(b2.y) << 16));
        p[3] = (int)((unsigned)f2bf(b2.z) | ((unsigned)f2bf(b2.w) << 16));
        *(i32x4*)&xs0[xrow * 72 + xseg * 8] = p;
    }
    __syncthreads();

    for (int kt = 0; kt < EMB; kt += 64) {
        unsigned short* xb = (kt & 64) ? xs1 : xs0;
        unsigned short* xn = (kt & 64) ? xs0 : xs1;
        // wave-private W staging (rows 48*ng .. 48*ng+47); within-wave lgkm ordering only
#pragma unroll
        for (int i = 0; i < 6; ++i) {
            int rowl = ng * 48 + i * 8 + (lane >> 3);
            int seg  = lane & 7;
            *(i32x4*)&Ws[rowl * 72 + seg * 8] =
                *(const i32x4*)&Wt[(size_t)rowl * 1024 + kt + seg * 8];
        }
        // prefetch next x tile into the other buffer
        if (t < 256 && kt + 64 < EMB) {
            float4 a = *(const float4*)&x[(size_t)(m0 + xrow) * EMB + kt + 64 + xseg * 8];
            float4 b2 = *(const float4*)&x[(size_t)(m0 + xrow) * EMB + kt + 64 + xseg * 8 + 4];
            i32x4 p;
            p[0] = (int)((unsigned)f2bf(a.x) | ((unsigned)f2bf(a.y) << 16));
            p[1] = (int)((unsigned)f2bf(a.z) | ((unsigned)f2bf(a.w) << 16));
            p[2] = (int)((unsigned)f2bf(b2.x) | ((unsigned)f2bf(b2.y) << 16));
            p[3] = (int)((unsigned)f2bf(b2.z) | ((unsigned)f2bf(b2.w) << 16));
            *(i32x4*)&xn[xrow * 72 + xseg * 8] = p;
        }
        // compute
#pragma unroll
        for (int ks = 0; ks < 2; ++ks) {
            bf16x8 aA[2], aB[3];
#pragma unroll
            for (int mt = 0; mt < 2; ++mt)
                aA[mt] = *(const bf16x8*)&xb[(mt * 16 + l16) * 72 + ks * 32 + quad * 8];
#pragma unroll
            for (int jt = 0; jt < 3; ++jt)
                aB[jt] = *(const bf16x8*)&Ws[((ng * 3 + jt) * 16 + l16) * 72 + ks * 32 + quad * 8];
#pragma unroll
            for (int mt = 0; mt < 2; ++mt)
#pragma unroll
                for (int jt = 0; jt < 3; ++jt)
                    acc[mt][jt] = __builtin_amdgcn_mfma_f32_16x16x32_bf16(
                        aA[mt], aB[jt], acc[mt][jt], 0, 0, 0);
        }
        __syncthreads();
    }

    // ---- epilogue: scatter to LDS (per-matrix layout), then coalesced copy out ----
    unsigned short* Cq = lds;                 // [32][136]
    unsigned short* Ck = lds + 32 * 136;      // [32][136]
    unsigned short* Cv = lds + 2 * 32 * 136;  // [128][40] transposed
#pragma unroll
    for (int mt = 0; mt < 2; ++mt)
#pragma unroll
        for (int jt = 0; jt < 3; ++jt) {
            int nt = ng * 3 + jt;
            int wm = nt >> 3, nl = nt & 7;
            if (wm < 2) {
                unsigned short* C = (wm == 0) ? Cq : Ck;
#pragma unroll
                for (int rr = 0; rr < 4; ++rr)
                    C[(mt * 16 + quad * 4 + rr) * 136 + nl * 16 + l16] =
                        f2bf(acc[mt][jt][rr]);
            } else {
                short4v p;
                p[0] = (short)f2bf(acc[mt][jt][0]); p[1] = (short)f2bf(acc[mt][jt][1]);
                p[2] = (short)f2bf(acc[mt][jt][2]); p[3] = (short)f2bf(acc[mt][jt][3]);
                *(short4v*)&Cv[(nl * 16 + l16) * 40 + mt * 16 + quad * 4] = p;
            }
        }
    __syncthreads();
    {   // q, k: 32 x 128 each -> 512 i32x4, one per thread
        int row = t >> 4, seg = t & 15;
        *(i32x4*)&qb[((size_t)(m0 + row)) * HD + seg * 8] = *(const i32x4*)&Cq[row * 136 + seg * 8];
        *(i32x4*)&kb[((size_t)(m0 + row)) * HD + seg * 8] = *(const i32x4*)&Ck[row * 136 + seg * 8];
    }
    {   // v^T: 128 x 32 -> 512 i32x4, one per thread
        const int b = m0 >> 12, s0 = m0 & 4095;
        int h = t >> 2, seg = t & 3;
        *(i32x4*)&vtb[(size_t)b * (HD * SEQ) + (size_t)h * SEQ + s0 + seg * 8] =
            *(const i32x4*)&Cv[h * 40 + seg * 8];
    }
}

// ---------------- Flash attention: split-KV, BQ=128, 8 waves, XCD-batch affinity ----------------
// grid 480 x 512 thr. bx -> slot=bx&7 (≈XCD), batch=slot>>1, jj=(bx>>3)*2+(slot&1).
// Each XCD sees one batch -> K/V (4 MB) stays L2-resident.
#define PADK 136
#define PADV 72
#define PADP 72

__global__ __launch_bounds__(512, 4) void flash_kernel(
    const unsigned short* __restrict__ qb, const unsigned short* __restrict__ kb,
    const unsigned short* __restrict__ vtb, unsigned short* __restrict__ Opart,
    float* __restrict__ mbuf, float* __restrict__ lbuf)
{
    __shared__ __align__(16) unsigned short Ks[64 * PADK];    // 17.4 KB
    __shared__ __align__(16) unsigned short Vt[128 * PADV];   // 18.4 KB
    __shared__ __align__(16) unsigned short Pt[128 * PADP];   // 18.4 KB

    const int bx   = blockIdx.x;
    const int slot = bx & 7, pp = bx >> 3;
    const int b    = slot >> 1;
    const int jj   = pp * 2 + (slot & 1);
    if (jj >= NJOBS) return;                 // dummy pad blocks (no barrier yet)

    const int t    = threadIdx.x;
    const int lane = t & 63, w = t >> 6;     // 8 waves
    const int quad = lane >> 4, l16 = lane & 15;

    // decode jj -> (qi, c): q-tile qi has ceil((qi+1)/5) chunks
    int qi = 0, s = 0;
    for (qi = 0; qi < 32; ++qi) {
        int cnt = (qi + 5) / 5;
        if (jj < s + cnt) break;
        s += cnt;
    }
    const int c    = jj - s;
    const int qrow = qi * 128 + w * 16 + l16;
    const int jmax = 2 * qi + 2;
    const int jbeg = c * CHUNK;
    const int jend = min(jbeg + CHUNK, jmax);

    bf16x8 qf[4];
    {
        const unsigned short* qp = qb + ((size_t)b * SEQ + qrow) * HD;
#pragma unroll
        for (int ks = 0; ks < 4; ++ks)
            qf[ks] = *(const bf16x8*)&qp[ks * 32 + quad * 8];
    }

    f32x4 O[8];
#pragma unroll
    for (int i = 0; i < 8; ++i) O[i] = (f32x4){0.f, 0.f, 0.f, 0.f};
    float m_run = -1e30f, l_run = 0.f;

    const unsigned short* kbb  = kb  + (size_t)b * SEQ * HD;
    const unsigned short* vtbb = vtb + (size_t)b * HD * SEQ;

    for (int j0 = jbeg; j0 < jend; ++j0) {
        __syncthreads();   // prior iteration's reads of Ks/Vt complete
#pragma unroll
        for (int i = 0; i < 2; ++i) {
            int gg = i * 512 + t;            // K: 1024 chunks of 16B
            i32x4 kd = *(const i32x4*)&kbb[(size_t)j0 * 64 * HD + (size_t)gg * 8];
            *(i32x4*)&Ks[(gg >> 4) * PADK + (gg & 15) * 8] = kd;
        }
#pragma unroll
        for (int i = 0; i < 2; ++i) {
            int gg = i * 512 + t;            // V^T: 1024 chunks
            i32x4 vd = *(const i32x4*)&vtbb[(size_t)(gg >> 3) * SEQ + j0 * 64 + (gg & 7) * 8];
            *(i32x4*)&Vt[(gg >> 3) * PADV + (gg & 7) * 8] = vd;
        }
        __syncthreads();

        // fully-masked tile for this wave? (kv_min > max qrow of wave) -> skip compute
        if (j0 * 64 > qi * 128 + w * 16 + 15) continue;

        // ---- S^T = K . Q^T ----
        f32x4 st[4];
#pragma unroll
        for (int mt = 0; mt < 4; ++mt) {
            f32x4 a = (f32x4){0.f, 0.f, 0.f, 0.f};
#pragma unroll
            for (int ks = 0; ks < 4; ++ks) {
                bf16x8 kf = *(const bf16x8*)&Ks[(mt * 16 + l16) * PADK + ks * 32 + quad * 8];
                a = __builtin_amdgcn_mfma_f32_16x16x32_bf16(kf, qf[ks], a, 0, 0, 0);
            }
            st[mt] = a;
        }

        // ---- causal mask (skip when tile fully valid for this wave) ----
        if (j0 * 64 + 63 > qi * 128 + w * 16) {
#pragma unroll
            for (int mt = 0; mt < 4; ++mt)
#pragma unroll
                for (int rr = 0; rr < 4; ++rr) {
                    int kv = j0 * 64 + mt * 16 + quad * 4 + rr;
                    if (kv > qrow) st[mt][rr] = -1e30f;
                }
        }
        // NOTE: rows with zero valid entries yield m=-1e30 garbage partials;
        // combine neutralizes them via wgt = exp(-1e30 - M) = 0.

        // ---- online softmax (lane owns one q-row) ----
        float mx = -1e30f;
#pragma unroll
        for (int mt = 0; mt < 4; ++mt)
#pragma unroll
            for (int rr = 0; rr < 4; ++rr) mx = fmaxf(mx, st[mt][rr]);
        mx = fmaxf(mx, __shfl_xor(mx, 16));
        mx = fmaxf(mx, __shfl_xor(mx, 32));
        const float m_new = fmaxf(m_run, mx);
        const float alpha = __expf(m_run - m_new);
        float psum = 0.f;
#pragma unroll
        for (int mt = 0; mt < 4; ++mt)
#pragma unroll
            for (int rr = 0; rr < 4; ++rr) {
                float p = __expf(st[mt][rr] - m_new);
                st[mt][rr] = p;
                psum += p;
            }
        psum += __shfl_xor(psum, 16);
        psum += __shfl_xor(psum, 32);
        m_run = m_new;
        l_run = l_run * alpha + psum;

        // ---- P^T -> LDS (wave-private rows; no barrier needed) ----
#pragma unroll
        for (int mt = 0; mt < 4; ++mt) {
            short4v p;
            p[0] = (short)f2bf(st[mt][0]); p[1] = (short)f2bf(st[mt][1]);
            p[2] = (short)f2bf(st[mt][2]); p[3] = (short)f2bf(st[mt][3]);
            *(short4v*)&Pt[(w * 16 + l16) * PADP + mt * 16 + quad * 4] = p;
        }

#pragma unroll
        for (int i = 0; i < 8; ++i) {
            O[i][0] *= alpha; O[i][1] *= alpha; O[i][2] *= alpha; O[i][3] *= alpha;
        }

        // ---- O^T += V^T . P^T ----
        bf16x8 pf0 = *(const bf16x8*)&Pt[(w * 16 + l16) * PADP + quad * 8];
        bf16x8 pf1 = *(const bf16x8*)&Pt[(w * 16 + l16) * PADP + 32 + quad * 8];
#pragma unroll
        for (int mt = 0; mt < 8; ++mt) {
            bf16x8 vf0 = *(const bf16x8*)&Vt[(mt * 16 + l16) * PADV + quad * 8];
            bf16x8 vf1 = *(const bf16x8*)&Vt[(mt * 16 + l16) * PADV + 32 + quad * 8];
            O[mt] = __builtin_amdgcn_mfma_f32_16x16x32_bf16(vf0, pf0, O[mt], 0, 0, 0);
            O[mt] = __builtin_amdgcn_mfma_f32_16x16x32_bf16(vf1, pf1, O[mt], 0, 0, 0);
        }
    }

    // ---- partial epilogue: unnormalized O (bf16) + m,l ----
    const int r = w * 16 + l16;
    const size_t jobbase = (size_t)b * NJOBS + jj;
    unsigned short* po = Opart + jobbase * (128 * 128) + (size_t)r * 128;
#pragma unroll
    for (int mt = 0; mt < 8; ++mt) {
        short4v p;
        p[0] = (short)f2bf(O[mt][0]); p[1] = (short)f2bf(O[mt][1]);
        p[2] = (short)f2bf(O[mt][2]); p[3] = (short)f2bf(O[mt][3]);
        *(short4v*)&po[mt * 16 + quad * 4] = p;
    }
    if (quad == 0) {
        mbuf[jobbase * 128 + r] = m_run;
        lbuf[jobbase * 128 + r] = l_run;
    }
}

// ---------------- Combine partials ----------------
// grid (32, 4) x 512 thr: thread -> q-row t>>2 (0..127), 32 head cols at (t&3)*32.
__global__ __launch_bounds__(512) void combine_kernel(
    const unsigned short* __restrict__ Opart, const float* __restrict__ mbuf,
    const float* __restrict__ lbuf, float* __restrict__ out)
{
    const int qi = blockIdx.x, b = blockIdx.y;
    const int nc = (qi + 5) / 5;
    int j0 = 0;
    for (int q = 0; q < qi; ++q) j0 += (q + 5) / 5;
    const int t = threadIdx.x;
    const int row = t >> 2, cg = (t & 3) * 32;

    float mv[MAXC], lv[MAXC];
    float M = -1e30f;
#pragma unroll
    for (int c2 = 0; c2 < MAXC; ++c2) {
        if (c2 < nc) {
            const size_t jb = (size_t)b * NJOBS + j0 + c2;
            mv[c2] = mbuf[jb * 128 + row];
            lv[c2] = lbuf[jb * 128 + row];
            M = fmaxf(M, mv[c2]);
        } else { mv[c2] = -1e30f; lv[c2] = 0.f; }
    }
    float L = 0.f;
#pragma unroll
    for (int c2 = 0; c2 < MAXC; ++c2)
        if (c2 < nc) L += __expf(mv[c2] - M) * lv[c2];
    const float Linv = 1.0f / L;

    float acc[32];
#pragma unroll
    for (int i = 0; i < 32; ++i) acc[i] = 0.f;
#pragma unroll
    for (int c2 = 0; c2 < MAXC; ++c2) {
        if (c2 < nc) {
            const float wgt = __expf(mv[c2] - M) * Linv;
            const unsigned short* po = Opart + ((size_t)b * NJOBS + j0 + c2) * (128 * 128) +
                                       (size_t)row * 128 + cg;
#pragma unroll
            for (int i = 0; i < 4; ++i) {
                i32x4 d = *(const i32x4*)&po[i * 8];
#pragma unroll
                for (int e = 0; e < 4; ++e) {
                    unsigned int u = (unsigned int)d[e];
                    acc[i * 8 + e * 2]     = fmaf(wgt, bf2f((unsigned short)(u & 0xffff)), acc[i * 8 + e * 2]);
                    acc[i * 8 + e * 2 + 1] = fmaf(wgt, bf2f((unsigned short)(u >> 16)),   acc[i * 8 + e * 2 + 1]);
                }
            }
        }
    }
    float* op = out + ((size_t)b * SEQ + qi * 128 + row) * HD + cg;
#pragma unroll
    for (int i = 0; i < 8; ++i) {
        float4 res;
        res.x = acc[i * 4]; res.y = acc[i * 4 + 1];
        res.z = acc[i * 4 + 2]; res.w = acc[i * 4 + 3];
        *(float4*)&op[i * 4] = res;
    }
}

extern "C" void kernel_launch(void* const* d_in, const int* in_sizes, int n_in,
                              void* d_out, int out_size, void* d_ws, size_t ws_size,
                              hipStream_t stream) {
    const float* x  = (const float*)d_in[0];
    const float* Wq = (const float*)d_in[1];
    const float* Wk = (const float*)d_in[2];
    const float* Wv = (const float*)d_in[3];

    unsigned short* qb    = (unsigned short*)d_ws;          // [16384][128] bf16
    unsigned short* kb    = qb  + (size_t)MROWS * HD;       // [16384][128] bf16
    unsigned short* vtb   = kb  + (size_t)MROWS * HD;       // [4][128][4096] bf16
    unsigned short* Wt    = vtb + (size_t)MROWS * HD;       // [3][128][1024] bf16
    unsigned short* Opart = Wt  + (size_t)3 * HD * EMB;     // [4][119][128][128] bf16
    float* mbuf = (float*)(Opart + (size_t)BATCH * NJOBS * 128 * 128);
    float* lbuf = mbuf + (size_t)BATCH * NJOBS * 128;
    float* out = (float*)d_out;

    wtrans_kernel <<<dim3(64, 3),  dim3(256), 0, stream>>>(Wq, Wk, Wv, Wt);
    qkv_kernel    <<<dim3(512),    dim3(512), 0, stream>>>(x, Wt, qb, kb, vtb);
    flash_kernel  <<<dim3(480),    dim3(512), 0, stream>>>(qb, kb, vtb, Opart, mbuf, lbuf);
    combine_kernel<<<dim3(32, 4),  dim3(512), 0, stream>>>(Opart, mbuf, lbuf, out);
}